// Round 1
// baseline (85.146 us; speedup 1.0000x reference)
//
#include <hip/hip_runtime.h>

// Problem: out[1024][1024] = relu(a @ feats^T) @ relu(b @ feats^T)^T
//   a,b: [1024][2048] fp32, feats: [128][2048] fp32, out fp32.
// Strategy: bf16 MFMA (16x16x32), 3 kernels:
//   zero_fk -> gemm1 (split-K atomic, fused fp32->bf16 staging) -> gemm2 (fused relu)

typedef __attribute__((ext_vector_type(8))) __bf16 bf16x8;
typedef __attribute__((ext_vector_type(4))) float floatx4;

#define KD   2048   // inner K of gemm1
#define NF   128    // feature count = K of gemm2
#define NA   1024   // rows of a (= rows of b = out dim)

static __device__ inline bf16x8 cvt8(float4 u, float4 v) {
    bf16x8 s;
    s[0] = (__bf16)u.x; s[1] = (__bf16)u.y; s[2] = (__bf16)u.z; s[3] = (__bf16)u.w;
    s[4] = (__bf16)v.x; s[5] = (__bf16)v.y; s[6] = (__bf16)v.z; s[7] = (__bf16)v.w;
    return s;
}

static __device__ inline bf16x8 cvt8_relu(float4 u, float4 v) {
    bf16x8 s;
    s[0] = (__bf16)fmaxf(u.x, 0.f); s[1] = (__bf16)fmaxf(u.y, 0.f);
    s[2] = (__bf16)fmaxf(u.z, 0.f); s[3] = (__bf16)fmaxf(u.w, 0.f);
    s[4] = (__bf16)fmaxf(v.x, 0.f); s[5] = (__bf16)fmaxf(v.y, 0.f);
    s[6] = (__bf16)fmaxf(v.z, 0.f); s[7] = (__bf16)fmaxf(v.w, 0.f);
    return s;
}

// ---- zero the fk accumulator (2048*128 fp32 = 64K float4) ----
__global__ __launch_bounds__(256) void zero_fk(float* __restrict__ fk) {
    int i = blockIdx.x * 256 + threadIdx.x;
    ((float4*)fk)[i] = make_float4(0.f, 0.f, 0.f, 0.f);
}

// ---- gemm1: fk[2048][128] += X[m, k0:k0+256] . feats[n, k0:k0+256]^T ----
// grid (32, 8): x = 64-row tile of [a;b], y = K-split of 256.
// block 256 threads = 4 waves; wave w covers n-cols [w*32, w*32+32).
__global__ __launch_bounds__(256) void gemm1(const float* __restrict__ A,
                                             const float* __restrict__ B,
                                             const float* __restrict__ F,
                                             float* __restrict__ fk) {
    __shared__ __bf16 Xs[64 * 40];    // 32 cols used, stride 40 (80B: 16B-aligned, 2-way-bank free)
    __shared__ __bf16 Fs[128 * 40];

    const int t    = threadIdx.x;
    const int m0   = blockIdx.x * 64;
    const int k0   = blockIdx.y * 256;
    const float* src = (m0 < NA) ? (A + (size_t)m0 * KD)
                                 : (B + (size_t)(m0 - NA) * KD);

    const int lane = t & 63;
    const int w    = t >> 6;
    const int ln   = lane & 15;
    const int quad = lane >> 4;
    const int q8   = quad * 8;

    floatx4 acc[4][2];
#pragma unroll
    for (int mt = 0; mt < 4; mt++)
#pragma unroll
        for (int nt = 0; nt < 2; nt++)
            acc[mt][nt] = (floatx4){0.f, 0.f, 0.f, 0.f};

    const int xrow = t >> 2, xcol = (t & 3) * 8;    // 64 rows x 32 cols, 8 floats/thread
    const int frow = t >> 1, fcol = (t & 1) * 16;   // 128 rows x 32 cols, 16 floats/thread

    for (int kk = 0; kk < 256; kk += 32) {
        // stage X chunk (fp32 -> bf16)
        {
            const float* p = src + (size_t)xrow * KD + (k0 + kk + xcol);
            float4 u = *(const float4*)p;
            float4 v = *(const float4*)(p + 4);
            *(bf16x8*)&Xs[xrow * 40 + xcol] = cvt8(u, v);
        }
        // stage feats chunk (fp32 -> bf16)
        {
            const float* p = F + (size_t)frow * KD + (k0 + kk + fcol);
            float4 u0 = *(const float4*)(p + 0);
            float4 u1 = *(const float4*)(p + 4);
            float4 u2 = *(const float4*)(p + 8);
            float4 u3 = *(const float4*)(p + 12);
            *(bf16x8*)&Fs[frow * 40 + fcol]     = cvt8(u0, u1);
            *(bf16x8*)&Fs[frow * 40 + fcol + 8] = cvt8(u2, u3);
        }
        __syncthreads();

        bf16x8 bfrag[2];
#pragma unroll
        for (int nt = 0; nt < 2; nt++)
            bfrag[nt] = *(const bf16x8*)&Fs[(w * 32 + nt * 16 + ln) * 40 + q8];
#pragma unroll
        for (int mt = 0; mt < 4; mt++) {
            bf16x8 af = *(const bf16x8*)&Xs[(mt * 16 + ln) * 40 + q8];
#pragma unroll
            for (int nt = 0; nt < 2; nt++)
                acc[mt][nt] = __builtin_amdgcn_mfma_f32_16x16x32_bf16(
                    af, bfrag[nt], acc[mt][nt], 0, 0, 0);
        }
        __syncthreads();
    }

    // epilogue: C/D layout col=lane&15, row=quad*4+reg
#pragma unroll
    for (int mt = 0; mt < 4; mt++)
#pragma unroll
        for (int nt = 0; nt < 2; nt++)
#pragma unroll
            for (int r = 0; r < 4; r++) {
                int row = m0 + mt * 16 + quad * 4 + r;
                int col = w * 32 + nt * 16 + ln;
                atomicAdd(&fk[row * NF + col], acc[mt][nt][r]);
            }
}

// ---- gemm2: out[i][j] = sum_f relu(fk[i][f]) * relu(fk[1024+j][f]) ----
// grid (16,16): x = 64-col tile (b rows), y = 64-row tile (a rows).
// block 256 = 4 waves in 2x2; full K=128 staged once.
__global__ __launch_bounds__(256) void gemm2(const float* __restrict__ fk,
                                             float* __restrict__ out) {
    __shared__ __bf16 Ps[64 * 136];   // stride 136 (272B: 16B-aligned, 2-way-bank free)
    __shared__ __bf16 Qs[64 * 136];

    const int t    = threadIdx.x;
    const int i0   = blockIdx.y * 64;   // a-row tile
    const int j0   = blockIdx.x * 64;   // b-row tile
    const int lane = t & 63;
    const int w    = t >> 6;
    const int wm   = w & 1;
    const int wn   = w >> 1;
    const int ln   = lane & 15;
    const int quad = lane >> 4;
    const int q8   = quad * 8;

    // stage P (a_fk rows) and Q (b_fk rows), fused relu + cvt
    const int prow = t >> 2, pcol = (t & 3) * 32;   // 64 rows x 128 cols, 32 floats/thread
    {
        const float* p = fk + (size_t)(i0 + prow) * NF + pcol;
        const float* q = fk + (size_t)(NA + j0 + prow) * NF + pcol;
#pragma unroll
        for (int c = 0; c < 32; c += 8) {
            float4 u = *(const float4*)(p + c);
            float4 v = *(const float4*)(p + c + 4);
            *(bf16x8*)&Ps[prow * 136 + pcol + c] = cvt8_relu(u, v);
            float4 x = *(const float4*)(q + c);
            float4 y = *(const float4*)(q + c + 4);
            *(bf16x8*)&Qs[prow * 136 + pcol + c] = cvt8_relu(x, y);
        }
    }
    __syncthreads();

    floatx4 acc[2][2];
#pragma unroll
    for (int mt = 0; mt < 2; mt++)
#pragma unroll
        for (int nt = 0; nt < 2; nt++)
            acc[mt][nt] = (floatx4){0.f, 0.f, 0.f, 0.f};

#pragma unroll
    for (int k0 = 0; k0 < 128; k0 += 32) {
        bf16x8 af[2], bf[2];
#pragma unroll
        for (int mt = 0; mt < 2; mt++)
            af[mt] = *(const bf16x8*)&Ps[(wm * 32 + mt * 16 + ln) * 136 + k0 + q8];
#pragma unroll
        for (int nt = 0; nt < 2; nt++)
            bf[nt] = *(const bf16x8*)&Qs[(wn * 32 + nt * 16 + ln) * 136 + k0 + q8];
#pragma unroll
        for (int mt = 0; mt < 2; mt++)
#pragma unroll
            for (int nt = 0; nt < 2; nt++)
                acc[mt][nt] = __builtin_amdgcn_mfma_f32_16x16x32_bf16(
                    af[mt], bf[nt], acc[mt][nt], 0, 0, 0);
    }

#pragma unroll
    for (int mt = 0; mt < 2; mt++)
#pragma unroll
        for (int nt = 0; nt < 2; nt++)
#pragma unroll
            for (int r = 0; r < 4; r++) {
                int row = i0 + wm * 32 + mt * 16 + quad * 4 + r;
                int col = j0 + wn * 32 + nt * 16 + ln;
                out[(size_t)row * 1024 + col] = acc[mt][nt][r];
            }
}

extern "C" void kernel_launch(void* const* d_in, const int* in_sizes, int n_in,
                              void* d_out, int out_size, void* d_ws, size_t ws_size,
                              hipStream_t stream) {
    const float* a     = (const float*)d_in[0];
    const float* b     = (const float*)d_in[1];
    const float* feats = (const float*)d_in[2];
    float* out = (float*)d_out;
    float* fk  = (float*)d_ws;   // 2048*128 fp32 = 1 MB accumulator

    zero_fk<<<256, 256, 0, stream>>>(fk);
    gemm1<<<dim3(32, 8), 256, 0, stream>>>(a, b, feats, fk);
    gemm2<<<dim3(16, 16), 256, 0, stream>>>(fk, out);
}

// Round 2
// 79.356 us; speedup vs baseline: 1.0730x; 1.0730x over previous
//
#include <hip/hip_runtime.h>

// Problem: out[1024][1024] = relu(a @ feats^T) @ relu(b @ feats^T)^T
//   a,b: [1024][2048] fp32, feats: [128][2048] fp32, out fp32.
// Pipeline (all atomic-free):
//   gemm1_part : [a;b] @ feats^T split-K(16) -> fp32 partials in d_ws
//   reduce_relu: sum 16 partials, relu, cvt -> bf16 fk[2048][128]
//   gemm2      : relu'd bf16 fk -> out via MFMA

typedef __attribute__((ext_vector_type(8))) __bf16 bf16x8;
typedef __attribute__((ext_vector_type(4))) __bf16 bf16x4;
typedef __attribute__((ext_vector_type(4))) float floatx4;

#define KD     2048   // inner K of gemm1
#define NF     128    // feature count = K of gemm2
#define NA     1024   // rows of a (= rows of b = out dim)
#define NPART  16     // K-splits (K=128 each)
#define FKN    (2048 * 128)

static __device__ inline bf16x8 cvt8(float4 u, float4 v) {
    bf16x8 s;
    s[0] = (__bf16)u.x; s[1] = (__bf16)u.y; s[2] = (__bf16)u.z; s[3] = (__bf16)u.w;
    s[4] = (__bf16)v.x; s[5] = (__bf16)v.y; s[6] = (__bf16)v.z; s[7] = (__bf16)v.w;
    return s;
}

// ---- gemm1_part: part[s][2048][128] = X[m, s*128:(s+1)*128] . feats[:, same]^T
// grid (32, 16): x = 64-row tile of [a;b], y = K-split. block = 4 waves;
// wave w covers n-cols [w*32, w*32+32).
__global__ __launch_bounds__(256) void gemm1_part(const float* __restrict__ A,
                                                  const float* __restrict__ B,
                                                  const float* __restrict__ F,
                                                  float* __restrict__ part) {
    __shared__ __bf16 Xs[64 * 40];    // 32 cols used, stride 40
    __shared__ __bf16 Fs[128 * 40];

    const int t    = threadIdx.x;
    const int m0   = blockIdx.x * 64;
    const int s    = blockIdx.y;
    const int k0   = s * 128;
    const float* src = (m0 < NA) ? (A + (size_t)m0 * KD)
                                 : (B + (size_t)(m0 - NA) * KD);

    const int lane = t & 63;
    const int w    = t >> 6;
    const int ln   = lane & 15;
    const int quad = lane >> 4;
    const int q8   = quad * 8;

    floatx4 acc[4][2];
#pragma unroll
    for (int mt = 0; mt < 4; mt++)
#pragma unroll
        for (int nt = 0; nt < 2; nt++)
            acc[mt][nt] = (floatx4){0.f, 0.f, 0.f, 0.f};

    const int xrow = t >> 2, xcol = (t & 3) * 8;    // 64 rows x 32 cols
    const int frow = t >> 1, fcol = (t & 1) * 16;   // 128 rows x 32 cols

#pragma unroll
    for (int kk = 0; kk < 128; kk += 32) {
        {
            const float* p = src + (size_t)xrow * KD + (k0 + kk + xcol);
            float4 u = *(const float4*)p;
            float4 v = *(const float4*)(p + 4);
            *(bf16x8*)&Xs[xrow * 40 + xcol] = cvt8(u, v);
        }
        {
            const float* p = F + (size_t)frow * KD + (k0 + kk + fcol);
            float4 u0 = *(const float4*)(p + 0);
            float4 u1 = *(const float4*)(p + 4);
            float4 u2 = *(const float4*)(p + 8);
            float4 u3 = *(const float4*)(p + 12);
            *(bf16x8*)&Fs[frow * 40 + fcol]     = cvt8(u0, u1);
            *(bf16x8*)&Fs[frow * 40 + fcol + 8] = cvt8(u2, u3);
        }
        __syncthreads();

        bf16x8 bfrag[2];
#pragma unroll
        for (int nt = 0; nt < 2; nt++)
            bfrag[nt] = *(const bf16x8*)&Fs[(w * 32 + nt * 16 + ln) * 40 + q8];
#pragma unroll
        for (int mt = 0; mt < 4; mt++) {
            bf16x8 af = *(const bf16x8*)&Xs[(mt * 16 + ln) * 40 + q8];
#pragma unroll
            for (int nt = 0; nt < 2; nt++)
                acc[mt][nt] = __builtin_amdgcn_mfma_f32_16x16x32_bf16(
                    af, bfrag[nt], acc[mt][nt], 0, 0, 0);
        }
        __syncthreads();
    }

    // plain stores to this split's private partial buffer
    float* pdst = part + (size_t)s * FKN;
#pragma unroll
    for (int mt = 0; mt < 4; mt++)
#pragma unroll
        for (int nt = 0; nt < 2; nt++)
#pragma unroll
            for (int r = 0; r < 4; r++) {
                int row = m0 + mt * 16 + quad * 4 + r;
                int col = w * 32 + nt * 16 + ln;
                pdst[(size_t)row * NF + col] = acc[mt][nt][r];
            }
}

// ---- reduce_relu: fkb[i] = bf16(relu(sum_s part[s][i])), vectorized x4 ----
__global__ __launch_bounds__(256) void reduce_relu(const float* __restrict__ part,
                                                   __bf16* __restrict__ fkb) {
    int idx = blockIdx.x * 256 + threadIdx.x;   // 65536 threads, 4 floats each
    size_t base = (size_t)idx * 4;
    float4 sum = make_float4(0.f, 0.f, 0.f, 0.f);
#pragma unroll
    for (int s = 0; s < NPART; s++) {
        float4 u = *(const float4*)(part + (size_t)s * FKN + base);
        sum.x += u.x; sum.y += u.y; sum.z += u.z; sum.w += u.w;
    }
    bf16x4 o;
    o[0] = (__bf16)fmaxf(sum.x, 0.f);
    o[1] = (__bf16)fmaxf(sum.y, 0.f);
    o[2] = (__bf16)fmaxf(sum.z, 0.f);
    o[3] = (__bf16)fmaxf(sum.w, 0.f);
    *(bf16x4*)(fkb + base) = o;
}

// ---- gemm2: out[i][j] = sum_f fkb[i][f] * fkb[1024+j][f] (already relu'd) ----
// grid (16,16): 64x64 out tiles; block = 4 waves in 2x2.
__global__ __launch_bounds__(256) void gemm2(const __bf16* __restrict__ fkb,
                                             float* __restrict__ out) {
    __shared__ __bf16 Ps[64 * 136];
    __shared__ __bf16 Qs[64 * 136];

    const int t    = threadIdx.x;
    const int i0   = blockIdx.y * 64;
    const int j0   = blockIdx.x * 64;
    const int lane = t & 63;
    const int w    = t >> 6;
    const int wm   = w & 1;
    const int wn   = w >> 1;
    const int ln   = lane & 15;
    const int quad = lane >> 4;
    const int q8   = quad * 8;

    // stage 64x128 bf16 rows of a_fk and b_fk
    const int prow = t >> 2, pcol = (t & 3) * 32;
    {
        const __bf16* p = fkb + (size_t)(i0 + prow) * NF + pcol;
        const __bf16* q = fkb + (size_t)(NA + j0 + prow) * NF + pcol;
#pragma unroll
        for (int c = 0; c < 32; c += 8) {
            *(bf16x8*)&Ps[prow * 136 + pcol + c] = *(const bf16x8*)(p + c);
            *(bf16x8*)&Qs[prow * 136 + pcol + c] = *(const bf16x8*)(q + c);
        }
    }
    __syncthreads();

    floatx4 acc[2][2];
#pragma unroll
    for (int mt = 0; mt < 2; mt++)
#pragma unroll
        for (int nt = 0; nt < 2; nt++)
            acc[mt][nt] = (floatx4){0.f, 0.f, 0.f, 0.f};

#pragma unroll
    for (int k0 = 0; k0 < 128; k0 += 32) {
        bf16x8 af[2], bf[2];
#pragma unroll
        for (int mt = 0; mt < 2; mt++)
            af[mt] = *(const bf16x8*)&Ps[(wm * 32 + mt * 16 + ln) * 136 + k0 + q8];
#pragma unroll
        for (int nt = 0; nt < 2; nt++)
            bf[nt] = *(const bf16x8*)&Qs[(wn * 32 + nt * 16 + ln) * 136 + k0 + q8];
#pragma unroll
        for (int mt = 0; mt < 2; mt++)
#pragma unroll
            for (int nt = 0; nt < 2; nt++)
                acc[mt][nt] = __builtin_amdgcn_mfma_f32_16x16x32_bf16(
                    af[mt], bf[nt], acc[mt][nt], 0, 0, 0);
    }

#pragma unroll
    for (int mt = 0; mt < 2; mt++)
#pragma unroll
        for (int nt = 0; nt < 2; nt++)
#pragma unroll
            for (int r = 0; r < 4; r++) {
                int row = i0 + wm * 32 + mt * 16 + quad * 4 + r;
                int col = j0 + wn * 32 + nt * 16 + ln;
                out[(size_t)row * 1024 + col] = acc[mt][nt][r];
            }
}

extern "C" void kernel_launch(void* const* d_in, const int* in_sizes, int n_in,
                              void* d_out, int out_size, void* d_ws, size_t ws_size,
                              hipStream_t stream) {
    const float* a     = (const float*)d_in[0];
    const float* b     = (const float*)d_in[1];
    const float* feats = (const float*)d_in[2];
    float* out = (float*)d_out;

    float*   part = (float*)d_ws;                            // 16 MB partials
    __bf16*  fkb  = (__bf16*)((char*)d_ws + (size_t)NPART * FKN * 4); // 512 KB bf16

    gemm1_part<<<dim3(32, NPART), 256, 0, stream>>>(a, b, feats, part);
    reduce_relu<<<256, 256, 0, stream>>>(part, fkb);
    gemm2<<<dim3(16, 16), 256, 0, stream>>>(fkb, out);
}